// Round 19
// baseline (85.670 us; speedup 1.0000x reference)
//
#include <hip/hip_runtime.h>
#include <hip/hip_fp16.h>

// Problem constants (from reference)
#define NN 50000
#define EE 800000
#define MAXDEG 64            // Poisson(16) max degree; P(deg>64) ~ 1e-18
#define NBUCK 98             // dst buckets: d>>9, 512 dsts each
#define BSHIFT 9
#define BMASK 511
#define CAP 9216             // staging capacity per bucket (mean 8192, +11 sigma)
#define AB_BLOCKS 1564       // interleaved: even = edge pass1 (782), odd = node (782)
#define HPAD 104             // padded histogram stride

typedef _Float16 f16x8 __attribute__((ext_vector_type(8)));
typedef _Float16 h8   __attribute__((ext_vector_type(8)));
typedef _Float16 h2v  __attribute__((ext_vector_type(2)));
typedef float    f32x4 __attribute__((ext_vector_type(4)));

union F4H { float4 f4; __half2 h2[4]; };
union H4  { float2 f2; h2v h2[2]; };

__device__ __forceinline__ float qdot4(h2v q01, h2v q23, h2v k01, h2v k23) {
#if __has_builtin(__builtin_amdgcn_fdot2)
    return __builtin_amdgcn_fdot2(q01, k01,
           __builtin_amdgcn_fdot2(q23, k23, 0.f, false), false);
#else
    return (float)q01[0] * (float)k01[0] + (float)q01[1] * (float)k01[1]
         + (float)q23[0] * (float)k23[0] + (float)q23[1] * (float)k23[1];
#endif
}

// ---------------------------------------------------------------------------
// Kernel 0: zero the 98 bucket cursors
// ---------------------------------------------------------------------------
__global__ void zero_kernel(int* __restrict__ gcursor)
{
    if (threadIdx.x < NBUCK) gcursor[threadIdx.x] = 0;
}

// ---------------------------------------------------------------------------
// Kernel A: edge pass-1 binning (even blocks) + node linears/pack (odd).
// ---------------------------------------------------------------------------
__global__ __launch_bounds__(256) void binpack_kernel(
    const float* __restrict__ feat,
    const float* __restrict__ Wk, const float* __restrict__ bk,
    const float* __restrict__ Ws, const float* __restrict__ bs,
    const float* __restrict__ q, const float* __restrict__ v,
    const int* __restrict__ src, const int* __restrict__ dst,
    __half2* __restrict__ ks,          // [N,64] (k, skip) pairs
    _Float16* __restrict__ qvh,        // [N,128]: q[64] | v[64]
    int* __restrict__ gcursor,
    int* __restrict__ staging)
{
    __shared__ f16x8 sFrag[16 * 64];       // node role (16 KB)
    __shared__ int hist[4][HPAD], gbase[4][HPAD];

    int tid = threadIdx.x, bid = blockIdx.x;
    int wave = tid >> 6, lane = tid & 63;

    if ((bid & 1) == 0) {
        // ---------------- edge pass-1 (binning, per-wave hist) ----------------
        for (int i = tid; i < 4 * HPAD; i += 256) hist[i / HPAD][i % HPAD] = 0;
        __syncthreads();

        int ebid  = bid >> 1;
        int ebase = ebid * 1024 + tid * 4;    // EE % 4 == 0 -> all-or-nothing
        int4 es, ed;
        int b0 = 0, b1 = 0, b2 = 0, b3 = 0, r0 = 0, r1 = 0, r2 = 0, r3 = 0;
        bool ev = ebase < EE;
        if (ev) {
            es = *(const int4*)(src + ebase);
            ed = *(const int4*)(dst + ebase);
            b0 = ed.x >> BSHIFT; r0 = atomicAdd(&hist[wave][b0], 1);
            b1 = ed.y >> BSHIFT; r1 = atomicAdd(&hist[wave][b1], 1);
            b2 = ed.z >> BSHIFT; r2 = atomicAdd(&hist[wave][b2], 1);
            b3 = ed.w >> BSHIFT; r3 = atomicAdd(&hist[wave][b3], 1);
        }
        __syncthreads();
        if (tid < NBUCK) {
            int h0 = hist[0][tid], h1 = hist[1][tid];
            int h2 = hist[2][tid], h3 = hist[3][tid];
            int tot = h0 + h1 + h2 + h3;
            int base = tot ? atomicAdd(gcursor + tid, tot) : 0;
            gbase[0][tid] = base;
            gbase[1][tid] = base + h0;
            gbase[2][tid] = base + h0 + h1;
            gbase[3][tid] = base + h0 + h1 + h2;
        }
        __syncthreads();
        if (ev) {
            int i0 = gbase[wave][b0] + r0; if (i0 < CAP) staging[b0 * CAP + i0] = (es.x << BSHIFT) | (ed.x & BMASK);
            int i1 = gbase[wave][b1] + r1; if (i1 < CAP) staging[b1 * CAP + i1] = (es.y << BSHIFT) | (ed.y & BMASK);
            int i2 = gbase[wave][b2] + r2; if (i2 < CAP) staging[b2 * CAP + i2] = (es.z << BSHIFT) | (ed.z & BMASK);
            int i3 = gbase[wave][b3] + r3; if (i3 < CAP) staging[b3 * CAP + i3] = (es.w << BSHIFT) | (ed.w & BMASK);
        }
        return;
    }

    // ---------------- node role: MFMA linears + qv split pack ----------------
    int nbid = bid >> 1;                      // 0..781

    for (int i = tid; i < 4096; i += 256) {
        int k = i >> 6, nk = i & 63;
        int kt = k >> 5, j = k & 7;
        int lf = ((k >> 3) & 3) * 16 + (nk & 15);
        ((_Float16*)&sFrag[((nk >> 4) * 2 + kt) * 64 + lf])[j]       = (_Float16)Wk[i];
        ((_Float16*)&sFrag[((4 + (nk >> 4)) * 2 + kt) * 64 + lf])[j] = (_Float16)Ws[i];
    }
    __syncthreads();

    int base16 = nbid * 64 + wave * 16;
    if (base16 < NN) {
        int m  = lane & 15;
        int kg = lane >> 4;
        const float* arow = feat + (size_t)(base16 + m) * 64 + kg * 8;
        float4 fa0 = *(const float4*)(arow + 0);
        float4 fa1 = *(const float4*)(arow + 4);
        float4 fa2 = *(const float4*)(arow + 32);
        float4 fa3 = *(const float4*)(arow + 36);
        f16x8 a0 = { (_Float16)fa0.x,(_Float16)fa0.y,(_Float16)fa0.z,(_Float16)fa0.w,
                     (_Float16)fa1.x,(_Float16)fa1.y,(_Float16)fa1.z,(_Float16)fa1.w };
        f16x8 a1 = { (_Float16)fa2.x,(_Float16)fa2.y,(_Float16)fa2.z,(_Float16)fa2.w,
                     (_Float16)fa3.x,(_Float16)fa3.y,(_Float16)fa3.z,(_Float16)fa3.w };

        f32x4 acc0={0,0,0,0}, acc1={0,0,0,0}, acc2={0,0,0,0}, acc3={0,0,0,0};
        f32x4 acc4={0,0,0,0}, acc5={0,0,0,0}, acc6={0,0,0,0}, acc7={0,0,0,0};

#define COLT(c, ACC) { \
        f16x8 b0 = sFrag[((c)*2 + 0) * 64 + lane]; \
        f16x8 b1 = sFrag[((c)*2 + 1) * 64 + lane]; \
        ACC = __builtin_amdgcn_mfma_f32_16x16x32_f16(a0, b0, ACC, 0, 0, 0); \
        ACC = __builtin_amdgcn_mfma_f32_16x16x32_f16(a1, b1, ACC, 0, 0, 0); }
        COLT(0, acc0) COLT(1, acc1) COLT(2, acc2) COLT(3, acc3)
        COLT(4, acc4) COLT(5, acc5) COLT(6, acc6) COLT(7, acc7)
#undef COLT

        int rbase = base16 + kg * 4;

#define STOREP(COFF, AK, AS) { \
        int col = (COFF) + m; float bbk = bk[col], bbs = bs[col]; \
        ks[(size_t)(rbase + 0) * 64 + col] = __floats2half2_rn(AK[0] + bbk, AS[0] + bbs); \
        ks[(size_t)(rbase + 1) * 64 + col] = __floats2half2_rn(AK[1] + bbk, AS[1] + bbs); \
        ks[(size_t)(rbase + 2) * 64 + col] = __floats2half2_rn(AK[2] + bbk, AS[2] + bbs); \
        ks[(size_t)(rbase + 3) * 64 + col] = __floats2half2_rn(AK[3] + bbk, AS[3] + bbs); }
        STOREP( 0, acc0, acc4) STOREP(16, acc1, acc5)
        STOREP(32, acc2, acc6) STOREP(48, acc3, acc7)
#undef STOREP
    }

    // qv split pack: 16 q-halves + 16 v-halves per thread (one node row each)
    {
        size_t g0 = (size_t)nbid * 4096 + (size_t)tid * 16;
        int node = (int)(g0 >> 6);
        int col0 = (int)(g0 & 63);
        if (node < NN) {
            const float4* qp = (const float4*)(q + g0);
            const float4* vp = (const float4*)(v + g0);
            float4 q0 = qp[0], q1 = qp[1], q2 = qp[2], q3 = qp[3];
            float4 v0 = vp[0], v1 = vp[1], v2 = vp[2], v3 = vp[3];
            h8 qa = { (_Float16)q0.x,(_Float16)q0.y,(_Float16)q0.z,(_Float16)q0.w,
                      (_Float16)q1.x,(_Float16)q1.y,(_Float16)q1.z,(_Float16)q1.w };
            h8 qb = { (_Float16)q2.x,(_Float16)q2.y,(_Float16)q2.z,(_Float16)q2.w,
                      (_Float16)q3.x,(_Float16)q3.y,(_Float16)q3.z,(_Float16)q3.w };
            h8 va = { (_Float16)v0.x,(_Float16)v0.y,(_Float16)v0.z,(_Float16)v0.w,
                      (_Float16)v1.x,(_Float16)v1.y,(_Float16)v1.z,(_Float16)v1.w };
            h8 vb = { (_Float16)v2.x,(_Float16)v2.y,(_Float16)v2.z,(_Float16)v2.w,
                      (_Float16)v3.x,(_Float16)v3.y,(_Float16)v3.z,(_Float16)v3.w };
            _Float16* row = qvh + (size_t)node * 128;
            *(h8*)(row + col0)          = qa;
            *(h8*)(row + col0 + 8)      = qb;
            *(h8*)(row + 64 + col0)     = va;
            *(h8*)(row + 64 + col0 + 8) = vb;
        }
    }
}

// ---------------------------------------------------------------------------
// Kernel B: pass-2 scatter, TWO blocks per bucket (bidirectional slot fill).
// ---------------------------------------------------------------------------
__global__ __launch_bounds__(256) void scatter_kernel(
    const int* __restrict__ staging, const int* __restrict__ gcursor,
    unsigned short* __restrict__ sorted_src,
    int* __restrict__ cntA, int* __restrict__ cntB)
{
    __shared__ int cnt[512];
    int b = blockIdx.x >> 1, half = blockIdx.x & 1, tid = threadIdx.x;
    cnt[tid] = 0; cnt[tid + 256] = 0;
    __syncthreads();

    int nE = gcursor[b];
    if (nE > CAP) nE = CAP;
    int lo = half ? (nE >> 1) : 0;
    int hi = half ? nE : (nE >> 1);

    if (half == 0) {
        for (int i = lo + tid; i < hi; i += 256) {
            int e  = staging[b * CAP + i];
            int dl = e & BMASK;
            int pos = atomicAdd(&cnt[dl], 1);
            if (pos < MAXDEG)
                sorted_src[(size_t)((b << BSHIFT) + dl) * MAXDEG + pos] =
                    (unsigned short)(e >> BSHIFT);
        }
    } else {
        for (int i = lo + tid; i < hi; i += 256) {
            int e  = staging[b * CAP + i];
            int dl = e & BMASK;
            int pos = atomicAdd(&cnt[dl], 1);
            int sl = MAXDEG - 1 - pos;
            if (sl >= 0)
                sorted_src[(size_t)((b << BSHIFT) + dl) * MAXDEG + sl] =
                    (unsigned short)(e >> BSHIFT);
        }
    }
    __syncthreads();

    int* cp = half ? cntB : cntA;
    int d0 = (b << BSHIFT) + tid;
    if (d0 < NN) cp[d0] = cnt[tid];
    int d1 = d0 + 256;
    if (d1 < NN) cp[d1] = cnt[tid + 256];
}

// ---------------------------------------------------------------------------
// Kernel C: gather aggregation + epilogue. One wave per node.
// 16 edges/iter as 4 streams, EACH stream gated by a WAVE-UNIFORM branch on
// both its loads and compute (dcount uniform -> scalar branch, no masked
// waste). Deg<=16 nodes (~53%): all loads issue up-front, 4-deep MLP, no
// loop. 1-deep prefetch of the next 16-edge batch for bigger nodes.
// Epilogue: variance via E[x^2]-mu^2 — (sum, sumsq) reduced as two
// INDEPENDENT interleaved shfl chains (one less serial DS-latency chain).
// softmax shift-invariance -> no segment-max pass (scores are O(5)).
// ---------------------------------------------------------------------------
__global__ __launch_bounds__(256) void gather_finalize_kernel(
    const _Float16* __restrict__ qvh,      // [N,128]: q[64] | v[64]
    const __half2*  __restrict__ ks,       // [N,64] (k, skip)
    const unsigned short* __restrict__ sorted_src,
    const int*     __restrict__ cntA,
    const int*     __restrict__ cntB,
    const float*   __restrict__ Wg,
    const float*   __restrict__ bg,
    const float*   __restrict__ gamma,
    const float*   __restrict__ beta,
    const float*   __restrict__ prelu_a,
    float* __restrict__ out, int n)
{
    int node = (blockIdx.x * 256 + threadIdx.x) >> 6;
    int lane = threadIdx.x & 63;
    if (node >= n) return;
    int g = lane >> 4;
    int w = lane & 15;
    int slot = w * 4;

    int cA = cntA[node];
    int dcount = cA + cntB[node];
    if (dcount > MAXDEG) dcount = MAXDEG;
    int sidx = (lane < cA) ? lane : (MAXDEG - 1 - (lane - cA));
    int s_all = (lane < dcount) ? (int)sorted_src[(size_t)node * MAXDEG + sidx] : 0;

    // (k, skip) unpack: one 16B load
    F4H ksr;
    ksr.f4 = *(const float4*)(ks + (size_t)node * 64 + slot);
    float2 ks0 = __half22float2(ksr.h2[0]);
    float2 ks1 = __half22float2(ksr.h2[1]);
    float2 ks2 = __half22float2(ksr.h2[2]);
    float2 ks3 = __half22float2(ksr.h2[3]);
    float4 sk4; sk4.x = ks0.y; sk4.y = ks1.y; sk4.z = ks2.y; sk4.w = ks3.y;
    h2v kh01 = { (_Float16)ks0.x, (_Float16)ks1.x };
    h2v kh23 = { (_Float16)ks2.x, (_Float16)ks3.x };

    float wg0a = Wg[slot],      wg1a = Wg[slot+1],      wg2a = Wg[slot+2],      wg3a = Wg[slot+3];
    float wg0b = Wg[64+slot],   wg1b = Wg[64+slot+1],   wg2b = Wg[64+slot+2],   wg3b = Wg[64+slot+3];
    float wg0c = Wg[128+slot],  wg1c = Wg[128+slot+1],  wg2c = Wg[128+slot+2],  wg3c = Wg[128+slot+3];
    float gm0 = gamma[slot], gm1 = gamma[slot+1], gm2 = gamma[slot+2], gm3 = gamma[slot+3];
    float bt0 = beta[slot],  bt1 = beta[slot+1],  bt2 = beta[slot+2],  bt3 = beta[slot+3];
    float bgv = bg[0];
    float al  = prelu_a[0];

    float den = 0.f;
    float acc0 = 0.f, acc1 = 0.f, acc2 = 0.f, acc3 = 0.f;

    // wave-uniform per-stream load: issue only streams with live edges
#define LOADS(EB, QX, VX, SID) \
    if ((EB) + (SID) * 4 < dcount) { \
        int s_ = __shfl(s_all, ((EB) + (SID) * 4 + g) & 63); \
        QX.f2 = *(const float2*)(qvh + (size_t)s_ * 128 + slot); \
        VX.f2 = *(const float2*)(qvh + (size_t)s_ * 128 + 64 + slot); \
    }
#define COMP(EB, QX, VX, SID) \
    if ((EB) + (SID) * 4 < dcount) { \
        float p = qdot4(QX.h2[0], QX.h2[1], kh01, kh23); \
        p += __shfl_xor(p, 1); \
        p += __shfl_xor(p, 2); \
        float ex = (((EB) + (SID) * 4 + g) < dcount) ? __expf(p * 0.25f) : 0.f; \
        den += ex; \
        acc0 = fmaf(ex, (float)VX.h2[0][0], acc0); \
        acc1 = fmaf(ex, (float)VX.h2[0][1], acc1); \
        acc2 = fmaf(ex, (float)VX.h2[1][0], acc2); \
        acc3 = fmaf(ex, (float)VX.h2[1][1], acc3); }

    H4 qA, vA, qB, vB, qC, vC, qD, vD;
    H4 q2A, v2A, q2B, v2B, q2C, v2C, q2D, v2D;
    LOADS(0, qA, vA, 0) LOADS(0, qB, vB, 1)
    LOADS(0, qC, vC, 2) LOADS(0, qD, vD, 3)

    for (int e0 = 0; e0 < dcount; e0 += 16) {
        bool more = (e0 + 16) < dcount;     // wave-uniform
        if (more) {
            LOADS(e0 + 16, q2A, v2A, 0) LOADS(e0 + 16, q2B, v2B, 1)
            LOADS(e0 + 16, q2C, v2C, 2) LOADS(e0 + 16, q2D, v2D, 3)
        }
        COMP(e0, qA, vA, 0) COMP(e0, qB, vB, 1)
        COMP(e0, qC, vC, 2) COMP(e0, qD, vD, 3)
        if (more) {
            qA = q2A; vA = v2A; qB = q2B; vB = v2B;
            qC = q2C; vC = v2C; qD = q2D; vD = v2D;
        }
    }
#undef LOADS
#undef COMP

    den  += __shfl_xor(den, 16);  den  += __shfl_xor(den, 32);
    acc0 += __shfl_xor(acc0, 16); acc0 += __shfl_xor(acc0, 32);
    acc1 += __shfl_xor(acc1, 16); acc1 += __shfl_xor(acc1, 32);
    acc2 += __shfl_xor(acc2, 16); acc2 += __shfl_xor(acc2, 32);
    acc3 += __shfl_xor(acc3, 16); acc3 += __shfl_xor(acc3, 32);

    float inv = (den > 0.f) ? 1.f / den : 0.f;
    float r0 = acc0 * inv, r1 = acc1 * inv, r2 = acc2 * inv, r3 = acc3 * inv;

    float gp = sk4.x * wg0a + r0 * wg0b + (sk4.x - r0) * wg0c
             + sk4.y * wg1a + r1 * wg1b + (sk4.y - r1) * wg1c
             + sk4.z * wg2a + r2 * wg2b + (sk4.z - r2) * wg2c
             + sk4.w * wg3a + r3 * wg3b + (sk4.w - r3) * wg3c;
    gp += __shfl_xor(gp, 1);
    gp += __shfl_xor(gp, 2);
    gp += __shfl_xor(gp, 4);
    gp += __shfl_xor(gp, 8);
    float gate = 1.f / (1.f + __expf(-(gp + bgv)));

    float m0 = gate * sk4.x + (1.f - gate) * r0;
    float m1 = gate * sk4.y + (1.f - gate) * r1;
    float m2 = gate * sk4.z + (1.f - gate) * r2;
    float m3 = gate * sk4.w + (1.f - gate) * r3;

    // LayerNorm via E[x^2] - mu^2: two INDEPENDENT interleaved shfl chains
    float s1 = m0 + m1 + m2 + m3;
    float s2 = m0 * m0 + m1 * m1 + m2 * m2 + m3 * m3;
    s1 += __shfl_xor(s1, 1); s2 += __shfl_xor(s2, 1);
    s1 += __shfl_xor(s1, 2); s2 += __shfl_xor(s2, 2);
    s1 += __shfl_xor(s1, 4); s2 += __shfl_xor(s2, 4);
    s1 += __shfl_xor(s1, 8); s2 += __shfl_xor(s2, 8);
    float mu  = s1 * (1.f / 64.f);
    float var = s2 * (1.f / 64.f) - mu * mu;
    float rs = rsqrtf(var + 1e-5f);

    float d0 = m0 - mu, d1 = m1 - mu, d2 = m2 - mu, d3 = m3 - mu;
    float y0 = d0 * rs * gm0 + bt0;
    float y1 = d1 * rs * gm1 + bt1;
    float y2 = d2 * rs * gm2 + bt2;
    float y3 = d3 * rs * gm3 + bt3;
    y0 = (y0 >= 0.f) ? y0 : al * y0;
    y1 = (y1 >= 0.f) ? y1 : al * y1;
    y2 = (y2 >= 0.f) ? y2 : al * y2;
    y3 = (y3 >= 0.f) ? y3 : al * y3;

    if (g == 0) {
        float4 o; o.x = y0; o.y = y1; o.z = y2; o.w = y3;
        *(float4*)(out + (size_t)node * 64 + slot) = o;
    }
}

// ---------------------------------------------------------------------------
extern "C" void kernel_launch(void* const* d_in, const int* in_sizes, int n_in,
                              void* d_out, int out_size, void* d_ws, size_t ws_size,
                              hipStream_t stream)
{
    const float* q_src  = (const float*)d_in[0];
    const float* v_src  = (const float*)d_in[1];
    const float* feat   = (const float*)d_in[2];
    const int*   src    = (const int*)d_in[3];
    const int*   dst    = (const int*)d_in[4];
    const float* Wk     = (const float*)d_in[5];
    const float* bk     = (const float*)d_in[6];
    const float* Wskip  = (const float*)d_in[7];
    const float* bskip  = (const float*)d_in[8];
    const float* Wgate  = (const float*)d_in[9];
    const float* bgate  = (const float*)d_in[10];
    const float* ln_g   = (const float*)d_in[11];
    const float* ln_b   = (const float*)d_in[12];
    const float* prelu  = (const float*)d_in[13];

    float* out = (float*)d_out;

    // workspace layout (A = 12.8 MB unit)
    char* ws = (char*)d_ws;
    const size_t A = (size_t)NN * 64 * 4;
    __half2*        ks         = (__half2*)(ws);                   // N*64 h2 (k,skip)
    _Float16*       qvh        = (_Float16*)(ws + A);              // N*128 h (q|v)
    unsigned short* sorted_src = (unsigned short*)(ws + 2 * A);    // N*64 u16
    size_t off = 2 * A + A / 2;
    int* cntA    = (int*)(ws + off);            off += (size_t)NN * 4;
    int* cntB    = (int*)(ws + off);            off += (size_t)NN * 4;
    int* gcursor = (int*)(ws + off);            off += 4096;
    int* staging = (int*)(ws + off);

    zero_kernel<<<1, 128, 0, stream>>>(gcursor);

    binpack_kernel<<<AB_BLOCKS, 256, 0, stream>>>(
        feat, Wk, bk, Wskip, bskip, q_src, v_src, src, dst,
        ks, qvh, gcursor, staging);

    scatter_kernel<<<NBUCK * 2, 256, 0, stream>>>(staging, gcursor,
                                                  sorted_src, cntA, cntB);

    int gblk = (NN * 64 + 255) / 256;   // one wave per node
    gather_finalize_kernel<<<gblk, 256, 0, stream>>>(qvh, ks,
                                                     sorted_src, cntA, cntB,
                                                     Wgate, bgate, ln_g, ln_b,
                                                     prelu, out, NN);
}

// Round 20
// 76.641 us; speedup vs baseline: 1.1178x; 1.1178x over previous
//
#include <hip/hip_runtime.h>
#include <hip/hip_fp16.h>

// Problem constants (from reference)
#define NN 50000
#define EE 800000
#define MAXDEG 64            // Poisson(16) max degree; P(deg>64) ~ 1e-18
#define NBUCK 98             // dst buckets: d>>9, 512 dsts each
#define BSHIFT 9
#define BMASK 511
#define CAP 9216             // staging capacity per bucket (mean 8192, +11 sigma)
#define AB_BLOCKS 1173       // period 3: bid%3==0 -> edge (391 x 2048 edges), else node (782)
#define HPAD 104             // padded histogram stride

typedef _Float16 f16x8 __attribute__((ext_vector_type(8)));
typedef _Float16 h8   __attribute__((ext_vector_type(8)));
typedef _Float16 h2v  __attribute__((ext_vector_type(2)));
typedef float    f32x4 __attribute__((ext_vector_type(4)));

union F4H { float4 f4; __half2 h2[4]; };
union H4  { float2 f2; h2v h2[2]; };

__device__ __forceinline__ float qdot4(h2v q01, h2v q23, h2v k01, h2v k23) {
#if __has_builtin(__builtin_amdgcn_fdot2)
    return __builtin_amdgcn_fdot2(q01, k01,
           __builtin_amdgcn_fdot2(q23, k23, 0.f, false), false);
#else
    return (float)q01[0] * (float)k01[0] + (float)q01[1] * (float)k01[1]
         + (float)q23[0] * (float)k23[0] + (float)q23[1] * (float)k23[1];
#endif
}

// ---------------------------------------------------------------------------
// Kernel 0: zero the 98 bucket cursors
// ---------------------------------------------------------------------------
__global__ void zero_kernel(int* __restrict__ gcursor)
{
    if (threadIdx.x < NBUCK) gcursor[threadIdx.x] = 0;
}

// ---------------------------------------------------------------------------
// Kernel A: edge pass-1 binning (bid%3==0) + node linears/pack (else).
// Edge role: 8 edges/thread (2048/block, 391 blocks) -> per-wave LDS
// histograms -> one global returning atomic per (block,bucket) -> staged
// sequential writes of packed (src<<9 | d&511) u32s.
// Node role: W->LDS f16 MFMA linears; ks = half2(k,skip); qv split q[64]|v[64].
// ---------------------------------------------------------------------------
__global__ __launch_bounds__(256) void binpack_kernel(
    const float* __restrict__ feat,
    const float* __restrict__ Wk, const float* __restrict__ bk,
    const float* __restrict__ Ws, const float* __restrict__ bs,
    const float* __restrict__ q, const float* __restrict__ v,
    const int* __restrict__ src, const int* __restrict__ dst,
    __half2* __restrict__ ks,          // [N,64] (k, skip) pairs
    _Float16* __restrict__ qvh,        // [N,128]: q[64] | v[64]
    int* __restrict__ gcursor,
    int* __restrict__ staging)
{
    __shared__ f16x8 sFrag[16 * 64];       // node role (16 KB)
    __shared__ int hist[4][HPAD], gbase[4][HPAD];

    int tid = threadIdx.x, bid = blockIdx.x;
    int wave = tid >> 6, lane = tid & 63;

    if (bid % 3 == 0) {
        // ---------------- edge pass-1 (binning, 8 edges/thread) ----------------
        for (int i = tid; i < 4 * HPAD; i += 256) hist[i / HPAD][i % HPAD] = 0;
        __syncthreads();

        int ebid  = bid / 3;                  // 0..390
        int ebase = ebid * 2048 + tid * 8;    // EE % 8 == 0 -> all-or-nothing
        int4 es0, ed0, es1, ed1;
        int b0=0,b1=0,b2=0,b3=0,b4=0,b5=0,b6=0,b7=0;
        int r0=0,r1=0,r2=0,r3=0,r4=0,r5=0,r6=0,r7=0;
        bool ev = ebase < EE;
        if (ev) {
            es0 = *(const int4*)(src + ebase);
            es1 = *(const int4*)(src + ebase + 4);
            ed0 = *(const int4*)(dst + ebase);
            ed1 = *(const int4*)(dst + ebase + 4);
            b0 = ed0.x >> BSHIFT; r0 = atomicAdd(&hist[wave][b0], 1);
            b1 = ed0.y >> BSHIFT; r1 = atomicAdd(&hist[wave][b1], 1);
            b2 = ed0.z >> BSHIFT; r2 = atomicAdd(&hist[wave][b2], 1);
            b3 = ed0.w >> BSHIFT; r3 = atomicAdd(&hist[wave][b3], 1);
            b4 = ed1.x >> BSHIFT; r4 = atomicAdd(&hist[wave][b4], 1);
            b5 = ed1.y >> BSHIFT; r5 = atomicAdd(&hist[wave][b5], 1);
            b6 = ed1.z >> BSHIFT; r6 = atomicAdd(&hist[wave][b6], 1);
            b7 = ed1.w >> BSHIFT; r7 = atomicAdd(&hist[wave][b7], 1);
        }
        __syncthreads();
        if (tid < NBUCK) {
            int h0 = hist[0][tid], h1 = hist[1][tid];
            int h2 = hist[2][tid], h3 = hist[3][tid];
            int tot = h0 + h1 + h2 + h3;
            int base = tot ? atomicAdd(gcursor + tid, tot) : 0;
            gbase[0][tid] = base;
            gbase[1][tid] = base + h0;
            gbase[2][tid] = base + h0 + h1;
            gbase[3][tid] = base + h0 + h1 + h2;
        }
        __syncthreads();
        if (ev) {
#define STG(B, R, S, D) { int i_ = gbase[wave][B] + (R); \
            if (i_ < CAP) staging[(B) * CAP + i_] = ((S) << BSHIFT) | ((D) & BMASK); }
            STG(b0, r0, es0.x, ed0.x) STG(b1, r1, es0.y, ed0.y)
            STG(b2, r2, es0.z, ed0.z) STG(b3, r3, es0.w, ed0.w)
            STG(b4, r4, es1.x, ed1.x) STG(b5, r5, es1.y, ed1.y)
            STG(b6, r6, es1.z, ed1.z) STG(b7, r7, es1.w, ed1.w)
#undef STG
        }
        return;
    }

    // ---------------- node role: MFMA linears + qv split pack ----------------
    int nbid = (bid / 3) * 2 + (bid % 3 - 1);     // 0..781

    for (int i = tid; i < 4096; i += 256) {
        int k = i >> 6, nk = i & 63;
        int kt = k >> 5, j = k & 7;
        int lf = ((k >> 3) & 3) * 16 + (nk & 15);
        ((_Float16*)&sFrag[((nk >> 4) * 2 + kt) * 64 + lf])[j]       = (_Float16)Wk[i];
        ((_Float16*)&sFrag[((4 + (nk >> 4)) * 2 + kt) * 64 + lf])[j] = (_Float16)Ws[i];
    }
    __syncthreads();

    int base16 = nbid * 64 + wave * 16;
    if (base16 < NN) {
        int m  = lane & 15;
        int kg = lane >> 4;
        const float* arow = feat + (size_t)(base16 + m) * 64 + kg * 8;
        float4 fa0 = *(const float4*)(arow + 0);
        float4 fa1 = *(const float4*)(arow + 4);
        float4 fa2 = *(const float4*)(arow + 32);
        float4 fa3 = *(const float4*)(arow + 36);
        f16x8 a0 = { (_Float16)fa0.x,(_Float16)fa0.y,(_Float16)fa0.z,(_Float16)fa0.w,
                     (_Float16)fa1.x,(_Float16)fa1.y,(_Float16)fa1.z,(_Float16)fa1.w };
        f16x8 a1 = { (_Float16)fa2.x,(_Float16)fa2.y,(_Float16)fa2.z,(_Float16)fa2.w,
                     (_Float16)fa3.x,(_Float16)fa3.y,(_Float16)fa3.z,(_Float16)fa3.w };

        f32x4 acc0={0,0,0,0}, acc1={0,0,0,0}, acc2={0,0,0,0}, acc3={0,0,0,0};
        f32x4 acc4={0,0,0,0}, acc5={0,0,0,0}, acc6={0,0,0,0}, acc7={0,0,0,0};

#define COLT(c, ACC) { \
        f16x8 b0 = sFrag[((c)*2 + 0) * 64 + lane]; \
        f16x8 b1 = sFrag[((c)*2 + 1) * 64 + lane]; \
        ACC = __builtin_amdgcn_mfma_f32_16x16x32_f16(a0, b0, ACC, 0, 0, 0); \
        ACC = __builtin_amdgcn_mfma_f32_16x16x32_f16(a1, b1, ACC, 0, 0, 0); }
        COLT(0, acc0) COLT(1, acc1) COLT(2, acc2) COLT(3, acc3)
        COLT(4, acc4) COLT(5, acc5) COLT(6, acc6) COLT(7, acc7)
#undef COLT

        int rbase = base16 + kg * 4;

#define STOREP(COFF, AK, AS) { \
        int col = (COFF) + m; float bbk = bk[col], bbs = bs[col]; \
        ks[(size_t)(rbase + 0) * 64 + col] = __floats2half2_rn(AK[0] + bbk, AS[0] + bbs); \
        ks[(size_t)(rbase + 1) * 64 + col] = __floats2half2_rn(AK[1] + bbk, AS[1] + bbs); \
        ks[(size_t)(rbase + 2) * 64 + col] = __floats2half2_rn(AK[2] + bbk, AS[2] + bbs); \
        ks[(size_t)(rbase + 3) * 64 + col] = __floats2half2_rn(AK[3] + bbk, AS[3] + bbs); }
        STOREP( 0, acc0, acc4) STOREP(16, acc1, acc5)
        STOREP(32, acc2, acc6) STOREP(48, acc3, acc7)
#undef STOREP
    }

    // qv split pack: 16 q-halves + 16 v-halves per thread (one node row each)
    {
        size_t g0 = (size_t)nbid * 4096 + (size_t)tid * 16;
        int node = (int)(g0 >> 6);
        int col0 = (int)(g0 & 63);
        if (node < NN) {
            const float4* qp = (const float4*)(q + g0);
            const float4* vp = (const float4*)(v + g0);
            float4 q0 = qp[0], q1 = qp[1], q2 = qp[2], q3 = qp[3];
            float4 v0 = vp[0], v1 = vp[1], v2 = vp[2], v3 = vp[3];
            h8 qa = { (_Float16)q0.x,(_Float16)q0.y,(_Float16)q0.z,(_Float16)q0.w,
                      (_Float16)q1.x,(_Float16)q1.y,(_Float16)q1.z,(_Float16)q1.w };
            h8 qb = { (_Float16)q2.x,(_Float16)q2.y,(_Float16)q2.z,(_Float16)q2.w,
                      (_Float16)q3.x,(_Float16)q3.y,(_Float16)q3.z,(_Float16)q3.w };
            h8 va = { (_Float16)v0.x,(_Float16)v0.y,(_Float16)v0.z,(_Float16)v0.w,
                      (_Float16)v1.x,(_Float16)v1.y,(_Float16)v1.z,(_Float16)v1.w };
            h8 vb = { (_Float16)v2.x,(_Float16)v2.y,(_Float16)v2.z,(_Float16)v2.w,
                      (_Float16)v3.x,(_Float16)v3.y,(_Float16)v3.z,(_Float16)v3.w };
            _Float16* row = qvh + (size_t)node * 128;
            *(h8*)(row + col0)          = qa;
            *(h8*)(row + col0 + 8)      = qb;
            *(h8*)(row + 64 + col0)     = va;
            *(h8*)(row + 64 + col0 + 8) = vb;
        }
    }
}

// ---------------------------------------------------------------------------
// Kernel B: pass-2 scatter, TWO blocks per bucket (bidirectional slot fill).
// ---------------------------------------------------------------------------
__global__ __launch_bounds__(256) void scatter_kernel(
    const int* __restrict__ staging, const int* __restrict__ gcursor,
    unsigned short* __restrict__ sorted_src,
    int* __restrict__ cntA, int* __restrict__ cntB)
{
    __shared__ int cnt[512];
    int b = blockIdx.x >> 1, half = blockIdx.x & 1, tid = threadIdx.x;
    cnt[tid] = 0; cnt[tid + 256] = 0;
    __syncthreads();

    int nE = gcursor[b];
    if (nE > CAP) nE = CAP;
    int lo = half ? (nE >> 1) : 0;
    int hi = half ? nE : (nE >> 1);

    if (half == 0) {
        for (int i = lo + tid; i < hi; i += 256) {
            int e  = staging[b * CAP + i];
            int dl = e & BMASK;
            int pos = atomicAdd(&cnt[dl], 1);
            if (pos < MAXDEG)
                sorted_src[(size_t)((b << BSHIFT) + dl) * MAXDEG + pos] =
                    (unsigned short)(e >> BSHIFT);
        }
    } else {
        for (int i = lo + tid; i < hi; i += 256) {
            int e  = staging[b * CAP + i];
            int dl = e & BMASK;
            int pos = atomicAdd(&cnt[dl], 1);
            int sl = MAXDEG - 1 - pos;
            if (sl >= 0)
                sorted_src[(size_t)((b << BSHIFT) + dl) * MAXDEG + sl] =
                    (unsigned short)(e >> BSHIFT);
        }
    }
    __syncthreads();

    int* cp = half ? cntB : cntA;
    int d0 = (b << BSHIFT) + tid;
    if (d0 < NN) cp[d0] = cnt[tid];
    int d1 = d0 + 256;
    if (d1 < NN) cp[d1] = cnt[tid + 256];
}

// ---------------------------------------------------------------------------
// Kernel C: gather aggregation + epilogue (R18 structure, proven 79 us).
// One wave per node; 8 edges/iter (2 streams), 1-deep prefetch, wave-uniform
// stream-B skip; fdot2 dot on split q|v rows. Epilogue variance via
// E[x^2]-mu^2 (two independent interleaved shfl chains).
// softmax shift-invariance -> no segment-max pass (scores are O(5)).
// ---------------------------------------------------------------------------
__global__ __launch_bounds__(256) void gather_finalize_kernel(
    const _Float16* __restrict__ qvh,      // [N,128]: q[64] | v[64]
    const __half2*  __restrict__ ks,       // [N,64] (k, skip)
    const unsigned short* __restrict__ sorted_src,
    const int*     __restrict__ cntA,
    const int*     __restrict__ cntB,
    const float*   __restrict__ Wg,
    const float*   __restrict__ bg,
    const float*   __restrict__ gamma,
    const float*   __restrict__ beta,
    const float*   __restrict__ prelu_a,
    float* __restrict__ out, int n)
{
    int node = (blockIdx.x * 256 + threadIdx.x) >> 6;
    int lane = threadIdx.x & 63;
    if (node >= n) return;
    int g = lane >> 4;
    int w = lane & 15;
    int slot = w * 4;

    int cA = cntA[node];
    int dcount = cA + cntB[node];
    if (dcount > MAXDEG) dcount = MAXDEG;
    int sidx = (lane < cA) ? lane : (MAXDEG - 1 - (lane - cA));
    int s_all = (lane < dcount) ? (int)sorted_src[(size_t)node * MAXDEG + sidx] : 0;

    // (k, skip) unpack: one 16B load
    F4H ksr;
    ksr.f4 = *(const float4*)(ks + (size_t)node * 64 + slot);
    float2 ks0 = __half22float2(ksr.h2[0]);
    float2 ks1 = __half22float2(ksr.h2[1]);
    float2 ks2 = __half22float2(ksr.h2[2]);
    float2 ks3 = __half22float2(ksr.h2[3]);
    float4 sk4; sk4.x = ks0.y; sk4.y = ks1.y; sk4.z = ks2.y; sk4.w = ks3.y;
    h2v kh01 = { (_Float16)ks0.x, (_Float16)ks1.x };
    h2v kh23 = { (_Float16)ks2.x, (_Float16)ks3.x };

    float wg0a = Wg[slot],      wg1a = Wg[slot+1],      wg2a = Wg[slot+2],      wg3a = Wg[slot+3];
    float wg0b = Wg[64+slot],   wg1b = Wg[64+slot+1],   wg2b = Wg[64+slot+2],   wg3b = Wg[64+slot+3];
    float wg0c = Wg[128+slot],  wg1c = Wg[128+slot+1],  wg2c = Wg[128+slot+2],  wg3c = Wg[128+slot+3];
    float gm0 = gamma[slot], gm1 = gamma[slot+1], gm2 = gamma[slot+2], gm3 = gamma[slot+3];
    float bt0 = beta[slot],  bt1 = beta[slot+1],  bt2 = beta[slot+2],  bt3 = beta[slot+3];
    float bgv = bg[0];
    float al  = prelu_a[0];

    float den = 0.f;
    float acc0 = 0.f, acc1 = 0.f, acc2 = 0.f, acc3 = 0.f;

    int niter = (dcount + 7) >> 3;
    if (niter > 0) {
        int sA = __shfl(s_all, g);
        int sB = __shfl(s_all, 4 + g);
        H4 qA, vA, qB, vB;
        qA.f2 = *(const float2*)(qvh + (size_t)sA * 128 + slot);
        vA.f2 = *(const float2*)(qvh + (size_t)sA * 128 + 64 + slot);
        qB.f2 = *(const float2*)(qvh + (size_t)sB * 128 + slot);
        vB.f2 = *(const float2*)(qvh + (size_t)sB * 128 + 64 + slot);

        for (int it = 0; it < niter; ++it) {
            H4 cqA = qA, cvA = vA, cqB = qB, cvB = vB;
            int e0 = it * 8;
            if (it + 1 < niter) {
                int sA2 = __shfl(s_all, (e0 + 8 + g) & 63);
                int sB2 = __shfl(s_all, (e0 + 12 + g) & 63);
                qA.f2 = *(const float2*)(qvh + (size_t)sA2 * 128 + slot);
                vA.f2 = *(const float2*)(qvh + (size_t)sA2 * 128 + 64 + slot);
                qB.f2 = *(const float2*)(qvh + (size_t)sB2 * 128 + slot);
                vB.f2 = *(const float2*)(qvh + (size_t)sB2 * 128 + 64 + slot);
            }

            {
                float p = qdot4(cqA.h2[0], cqA.h2[1], kh01, kh23);
                p += __shfl_xor(p, 1);
                p += __shfl_xor(p, 2);
                float ex = ((e0 + g) < dcount) ? __expf(p * 0.25f) : 0.f;
                den += ex;
                acc0 = fmaf(ex, (float)cvA.h2[0][0], acc0);
                acc1 = fmaf(ex, (float)cvA.h2[0][1], acc1);
                acc2 = fmaf(ex, (float)cvA.h2[1][0], acc2);
                acc3 = fmaf(ex, (float)cvA.h2[1][1], acc3);
            }

            if (e0 + 4 < dcount) {   // wave-uniform: skip fully-masked stream B
                float p = qdot4(cqB.h2[0], cqB.h2[1], kh01, kh23);
                p += __shfl_xor(p, 1);
                p += __shfl_xor(p, 2);
                float ex = ((e0 + 4 + g) < dcount) ? __expf(p * 0.25f) : 0.f;
                den += ex;
                acc0 = fmaf(ex, (float)cvB.h2[0][0], acc0);
                acc1 = fmaf(ex, (float)cvB.h2[0][1], acc1);
                acc2 = fmaf(ex, (float)cvB.h2[1][0], acc2);
                acc3 = fmaf(ex, (float)cvB.h2[1][1], acc3);
            }
        }
    }

    den  += __shfl_xor(den, 16);  den  += __shfl_xor(den, 32);
    acc0 += __shfl_xor(acc0, 16); acc0 += __shfl_xor(acc0, 32);
    acc1 += __shfl_xor(acc1, 16); acc1 += __shfl_xor(acc1, 32);
    acc2 += __shfl_xor(acc2, 16); acc2 += __shfl_xor(acc2, 32);
    acc3 += __shfl_xor(acc3, 16); acc3 += __shfl_xor(acc3, 32);

    float inv = (den > 0.f) ? 1.f / den : 0.f;
    float r0 = acc0 * inv, r1 = acc1 * inv, r2 = acc2 * inv, r3 = acc3 * inv;

    float gp = sk4.x * wg0a + r0 * wg0b + (sk4.x - r0) * wg0c
             + sk4.y * wg1a + r1 * wg1b + (sk4.y - r1) * wg1c
             + sk4.z * wg2a + r2 * wg2b + (sk4.z - r2) * wg2c
             + sk4.w * wg3a + r3 * wg3b + (sk4.w - r3) * wg3c;
    gp += __shfl_xor(gp, 1);
    gp += __shfl_xor(gp, 2);
    gp += __shfl_xor(gp, 4);
    gp += __shfl_xor(gp, 8);
    float gate = 1.f / (1.f + __expf(-(gp + bgv)));

    float m0 = gate * sk4.x + (1.f - gate) * r0;
    float m1 = gate * sk4.y + (1.f - gate) * r1;
    float m2 = gate * sk4.z + (1.f - gate) * r2;
    float m3 = gate * sk4.w + (1.f - gate) * r3;

    // LayerNorm via E[x^2] - mu^2: two INDEPENDENT interleaved shfl chains
    float s1 = m0 + m1 + m2 + m3;
    float s2 = m0 * m0 + m1 * m1 + m2 * m2 + m3 * m3;
    s1 += __shfl_xor(s1, 1); s2 += __shfl_xor(s2, 1);
    s1 += __shfl_xor(s1, 2); s2 += __shfl_xor(s2, 2);
    s1 += __shfl_xor(s1, 4); s2 += __shfl_xor(s2, 4);
    s1 += __shfl_xor(s1, 8); s2 += __shfl_xor(s2, 8);
    float mu  = s1 * (1.f / 64.f);
    float var = s2 * (1.f / 64.f) - mu * mu;
    float rs = rsqrtf(var + 1e-5f);

    float d0 = m0 - mu, d1 = m1 - mu, d2 = m2 - mu, d3 = m3 - mu;
    float y0 = d0 * rs * gm0 + bt0;
    float y1 = d1 * rs * gm1 + bt1;
    float y2 = d2 * rs * gm2 + bt2;
    float y3 = d3 * rs * gm3 + bt3;
    y0 = (y0 >= 0.f) ? y0 : al * y0;
    y1 = (y1 >= 0.f) ? y1 : al * y1;
    y2 = (y2 >= 0.f) ? y2 : al * y2;
    y3 = (y3 >= 0.f) ? y3 : al * y3;

    if (g == 0) {
        float4 o; o.x = y0; o.y = y1; o.z = y2; o.w = y3;
        *(float4*)(out + (size_t)node * 64 + slot) = o;
    }
}

// ---------------------------------------------------------------------------
extern "C" void kernel_launch(void* const* d_in, const int* in_sizes, int n_in,
                              void* d_out, int out_size, void* d_ws, size_t ws_size,
                              hipStream_t stream)
{
    const float* q_src  = (const float*)d_in[0];
    const float* v_src  = (const float*)d_in[1];
    const float* feat   = (const float*)d_in[2];
    const int*   src    = (const int*)d_in[3];
    const int*   dst    = (const int*)d_in[4];
    const float* Wk     = (const float*)d_in[5];
    const float* bk     = (const float*)d_in[6];
    const float* Wskip  = (const float*)d_in[7];
    const float* bskip  = (const float*)d_in[8];
    const float* Wgate  = (const float*)d_in[9];
    const float* bgate  = (const float*)d_in[10];
    const float* ln_g   = (const float*)d_in[11];
    const float* ln_b   = (const float*)d_in[12];
    const float* prelu  = (const float*)d_in[13];

    float* out = (float*)d_out;

    // workspace layout (A = 12.8 MB unit)
    char* ws = (char*)d_ws;
    const size_t A = (size_t)NN * 64 * 4;
    __half2*        ks         = (__half2*)(ws);                   // N*64 h2 (k,skip)
    _Float16*       qvh        = (_Float16*)(ws + A);              // N*128 h (q|v)
    unsigned short* sorted_src = (unsigned short*)(ws + 2 * A);    // N*64 u16
    size_t off = 2 * A + A / 2;
    int* cntA    = (int*)(ws + off);            off += (size_t)NN * 4;
    int* cntB    = (int*)(ws + off);            off += (size_t)NN * 4;
    int* gcursor = (int*)(ws + off);            off += 4096;
    int* staging = (int*)(ws + off);

    zero_kernel<<<1, 128, 0, stream>>>(gcursor);

    binpack_kernel<<<AB_BLOCKS, 256, 0, stream>>>(
        feat, Wk, bk, Wskip, bskip, q_src, v_src, src, dst,
        ks, qvh, gcursor, staging);

    scatter_kernel<<<NBUCK * 2, 256, 0, stream>>>(staging, gcursor,
                                                  sorted_src, cntA, cntB);

    int gblk = (NN * 64 + 255) / 256;   // one wave per node
    gather_finalize_kernel<<<gblk, 256, 0, stream>>>(qvh, ks,
                                                     sorted_src, cntA, cntB,
                                                     Wgate, bgate, ln_g, ln_b,
                                                     prelu, out, NN);
}